// Round 2
// baseline (1127.822 us; speedup 1.0000x reference)
//
#include <hip/hip_runtime.h>

#define TT 2048
#define BB 512
#define HH 64

// 64-lane full-wave sum via DPP butterfly + scan-bcast; full sum valid in lane 63.
__device__ __forceinline__ float wave_sum_dpp(float v) {
    float t;
    // xor1: quad_perm [1,0,3,2] = 0xB1
    t = __int_as_float(__builtin_amdgcn_update_dpp(0, __float_as_int(v), 0xB1, 0xF, 0xF, false));
    v += t;
    // xor2: quad_perm [2,3,0,1] = 0x4E
    t = __int_as_float(__builtin_amdgcn_update_dpp(0, __float_as_int(v), 0x4E, 0xF, 0xF, false));
    v += t;
    // xor4: half_mirror
    t = __int_as_float(__builtin_amdgcn_update_dpp(0, __float_as_int(v), 0x141, 0xF, 0xF, false));
    v += t;
    // xor8: row_mirror
    t = __int_as_float(__builtin_amdgcn_update_dpp(0, __float_as_int(v), 0x140, 0xF, 0xF, false));
    v += t;
    // row_bcast15
    t = __int_as_float(__builtin_amdgcn_update_dpp(0, __float_as_int(v), 0x142, 0xF, 0xF, false));
    v += t;
    // row_bcast31
    t = __int_as_float(__builtin_amdgcn_update_dpp(0, __float_as_int(v), 0x143, 0xF, 0xF, false));
    v += t;
    return v;  // lane 63 holds the full 64-lane sum
}

__global__ __launch_bounds__(64, 1) void rnn_fused(
    const float* __restrict__ x,     // [T][B]
    const float* __restrict__ h0,    // [B][H]
    const float* __restrict__ Wih,   // [H]
    const float* __restrict__ Whh,   // [H][H]
    const float* __restrict__ bih,   // [H]
    const float* __restrict__ bhh,   // [H]
    const float* __restrict__ Wlin,  // [H]
    const float* __restrict__ blin,  // [1]
    float* __restrict__ y,           // [T][B]
    float* __restrict__ hN)          // [B][H]
{
    __shared__ float hsh[HH];

    const int b = blockIdx.x;   // batch element, 0..511
    const int h = threadIdx.x;  // hidden index (lane), 0..63

    // Per-lane recurrent weight row W_hh[h][0..63] in registers.
    float w[HH];
#pragma unroll
    for (int k = 0; k < HH; k += 4) {
        const float4 v4 = *reinterpret_cast<const float4*>(Whh + h * HH + k);
        w[k + 0] = v4.x; w[k + 1] = v4.y; w[k + 2] = v4.z; w[k + 3] = v4.w;
    }
    const float wih  = Wih[h];
    const float bias = bih[h] + bhh[h];
    const float wlin = Wlin[h];
    const float bl   = blin[0];

    float hval = h0[b * HH + h];

    const float* xb = x + b;  // x[t*BB + b]

    // Prefetch ring, statically indexed (depth 4).
    float xbuf0 = xb[0 * BB];
    float xbuf1 = xb[1 * BB];
    float xbuf2 = xb[2 * BB];
    float xbuf3 = xb[3 * BB];

#pragma unroll 1
    for (int t = 0; t < TT; t += 4) {
#pragma unroll
        for (int u = 0; u < 4; ++u) {
            const int tt = t + u;
            float xt;
            if (u == 0) xt = xbuf0;
            else if (u == 1) xt = xbuf1;
            else if (u == 2) xt = xbuf2;
            else xt = xbuf3;
            const int tn = tt + 4;
            if (tn < TT) {
                const float xl = xb[tn * BB];
                if (u == 0) xbuf0 = xl;
                else if (u == 1) xbuf1 = xl;
                else if (u == 2) xbuf2 = xl;
                else xbuf3 = xl;
            }

            // Broadcast h_prev to all lanes via LDS: lane-strided write (free),
            // then wave-uniform ds_read_b128 (HW broadcast, conflict-free).
            // Same-wave LDS ops are in-order: no barrier needed (1 wave/block).
            hsh[h] = hval;
            float hb[HH];
#pragma unroll
            for (int k = 0; k < HH; k += 4) {
                const float4 v4 = *reinterpret_cast<const float4*>(&hsh[k]);
                hb[k + 0] = v4.x; hb[k + 1] = v4.y; hb[k + 2] = v4.z; hb[k + 3] = v4.w;
            }

            // dot(h_prev, W_hh[h][:]) — all-VGPR fmas, 4 independent chains
            float a0 = 0.f, a1 = 0.f, a2 = 0.f, a3 = 0.f;
#pragma unroll
            for (int k = 0; k < HH; k += 4) {
                a0 = fmaf(hb[k + 0], w[k + 0], a0);
                a1 = fmaf(hb[k + 1], w[k + 1], a1);
                a2 = fmaf(hb[k + 2], w[k + 2], a2);
                a3 = fmaf(hb[k + 3], w[k + 3], a3);
            }
            const float acc = fmaf(xt, wih, bias) + ((a0 + a1) + (a2 + a3));

            // tanh(acc) = 1 - 2/(e^{2acc}+1); saturates correctly for |acc| large
            const float e2 = __expf(acc + acc);
            hval = 1.0f - __fdividef(2.0f, e2 + 1.0f);

            // y[tt][b] = sum_h hval*wlin + b_lin  (off the critical path)
            float s = wave_sum_dpp(hval * wlin);
            if (h == 63) {
                y[tt * BB + b] = s + bl;
            }
        }
    }

    hN[b * HH + h] = hval;
}

extern "C" void kernel_launch(void* const* d_in, const int* in_sizes, int n_in,
                              void* d_out, int out_size, void* d_ws, size_t ws_size,
                              hipStream_t stream) {
    const float* x    = (const float*)d_in[0];
    const float* h0   = (const float*)d_in[1];
    const float* Wih  = (const float*)d_in[2];
    const float* Whh  = (const float*)d_in[3];
    const float* bih  = (const float*)d_in[4];
    const float* bhh  = (const float*)d_in[5];
    const float* Wlin = (const float*)d_in[6];
    const float* blin = (const float*)d_in[7];

    float* y  = (float*)d_out;            // [T*B]
    float* hN = (float*)d_out + TT * BB;  // [B*H]

    rnn_fused<<<dim3(BB), dim3(HH), 0, stream>>>(x, h0, Wih, Whh, bih, bhh, Wlin, blin, y, hN);
}

// Round 4
// 654.415 us; speedup vs baseline: 1.7234x; 1.7234x over previous
//
#include <hip/hip_runtime.h>

#define TT 2048
#define BB 512
#define HH 64

// 64-lane full-wave sum via DPP butterfly + scan-bcast; full sum valid in lane 63.
__device__ __forceinline__ float wave_sum_dpp(float v) {
    float t;
    t = __int_as_float(__builtin_amdgcn_update_dpp(0, __float_as_int(v), 0xB1, 0xF, 0xF, false)); // xor1
    v += t;
    t = __int_as_float(__builtin_amdgcn_update_dpp(0, __float_as_int(v), 0x4E, 0xF, 0xF, false)); // xor2
    v += t;
    t = __int_as_float(__builtin_amdgcn_update_dpp(0, __float_as_int(v), 0x141, 0xF, 0xF, false)); // half_mirror = xor4
    v += t;
    t = __int_as_float(__builtin_amdgcn_update_dpp(0, __float_as_int(v), 0x140, 0xF, 0xF, false)); // row_mirror = xor8
    v += t;
    t = __int_as_float(__builtin_amdgcn_update_dpp(0, __float_as_int(v), 0x142, 0xF, 0xF, false)); // row_bcast15
    v += t;
    t = __int_as_float(__builtin_amdgcn_update_dpp(0, __float_as_int(v), 0x143, 0xF, 0xF, false)); // row_bcast31
    v += t;
    return v;  // lane 63 holds the full 64-lane sum
}

__global__ __launch_bounds__(64, 1) void rnn_fused(
    const float* __restrict__ x,     // [T][B]
    const float* __restrict__ h0,    // [B][H]
    const float* __restrict__ Wih,   // [H]
    const float* __restrict__ Whh,   // [H][H]
    const float* __restrict__ bih,   // [H]
    const float* __restrict__ bhh,   // [H]
    const float* __restrict__ Wlin,  // [H]
    const float* __restrict__ blin,  // [1]
    float* __restrict__ y,           // [T][B]
    float* __restrict__ hN)          // [B][H]
{
    __shared__ float xsh[TT];   // this block's x column
    __shared__ float ysh[TT];   // per-step y results, dumped at end
    __shared__ float hsh[HH];   // h broadcast buffer

    const int b = blockIdx.x;   // batch element, 0..511
    const int h = threadIdx.x;  // hidden index (lane), 0..63

    // ---- Prologue: stage x[:, b] into LDS (32 independent loads/lane) ----
    const float* xb = x + b;
#pragma unroll
    for (int i = 0; i < TT / HH; ++i) {
        xsh[i * HH + h] = xb[(size_t)(i * HH + h) * BB];
    }

    // Per-lane recurrent weight row W_hh[h][0..63] in registers.
    float w[HH];
#pragma unroll
    for (int k = 0; k < HH; k += 4) {
        const float4 v4 = *reinterpret_cast<const float4*>(Whh + h * HH + k);
        w[k + 0] = v4.x; w[k + 1] = v4.y; w[k + 2] = v4.z; w[k + 3] = v4.w;
    }
    const float wih  = Wih[h];
    const float bias = bih[h] + bhh[h];
    const float wlin = Wlin[h];
    const float bl   = blin[0];

    float hval = h0[b * HH + h];
    hsh[h] = hval;  // seed broadcast buffer for step 0

    // ---- Recurrence: zero global-memory ops inside ----
#pragma unroll 1
    for (int t = 0; t < TT; t += 4) {
#pragma unroll
        for (int u = 0; u < 4; ++u) {
            const int tt = t + u;

            // Broadcast read of h_prev (wave-uniform ds_read_b128 = HW broadcast).
            // Same-wave LDS ops are processed in order: no barrier (1 wave/block).
            float hb[HH];
#pragma unroll
            for (int k = 0; k < HH; k += 4) {
                const float4 v4 = *reinterpret_cast<const float4*>(&hsh[k]);
                hb[k + 0] = v4.x; hb[k + 1] = v4.y; hb[k + 2] = v4.z; hb[k + 3] = v4.w;
            }

            const float xt = xsh[tt];

            // dot(h_prev, W_hh[h][:]) — all-VGPR fmas, 4 independent chains
            float a0 = 0.f, a1 = 0.f, a2 = 0.f, a3 = 0.f;
#pragma unroll
            for (int k = 0; k < HH; k += 4) {
                a0 = fmaf(hb[k + 0], w[k + 0], a0);
                a1 = fmaf(hb[k + 1], w[k + 1], a1);
                a2 = fmaf(hb[k + 2], w[k + 2], a2);
                a3 = fmaf(hb[k + 3], w[k + 3], a3);
            }
            const float acc = fmaf(xt, wih, bias) + ((a0 + a1) + (a2 + a3));

            // tanh(acc) = 1 - 2/(e^{2acc}+1); saturates correctly for |acc| large
            const float e2 = __expf(acc + acc);
            hval = 1.0f - __fdividef(2.0f, e2 + 1.0f);

            // publish h for next step
            hsh[h] = hval;

            // y[tt] = sum_h hval*wlin + b_lin  (side output, off recurrence path)
            float s = wave_sum_dpp(hval * wlin);
            if (h == 63) {
                ysh[tt] = s + bl;
            }
        }
    }

    // ---- Epilogue: dump y column and final h ----
#pragma unroll
    for (int i = 0; i < TT / HH; ++i) {
        y[(size_t)(i * HH + h) * BB + b] = ysh[i * HH + h];
    }
    hN[b * HH + h] = hval;
}

extern "C" void kernel_launch(void* const* d_in, const int* in_sizes, int n_in,
                              void* d_out, int out_size, void* d_ws, size_t ws_size,
                              hipStream_t stream) {
    const float* x    = (const float*)d_in[0];
    const float* h0   = (const float*)d_in[1];
    const float* Wih  = (const float*)d_in[2];
    const float* Whh  = (const float*)d_in[3];
    const float* bih  = (const float*)d_in[4];
    const float* bhh  = (const float*)d_in[5];
    const float* Wlin = (const float*)d_in[6];
    const float* blin = (const float*)d_in[7];

    float* y  = (float*)d_out;            // [T*B]
    float* hN = (float*)d_out + TT * BB;  // [B*H]

    rnn_fused<<<dim3(BB), dim3(HH), 0, stream>>>(x, h0, Wih, Whh, bih, bhh, Wlin, blin, y, hN);
}

// Round 5
// 529.044 us; speedup vs baseline: 2.1318x; 1.2370x over previous
//
#include <hip/hip_runtime.h>

#define TT 2048
#define BB 512
#define HH 64
#define NW 4
#define NTH (NW * 64)

// quad/full-wave DPP helpers (ctrl must be literal for the builtin)
#define DPP_ADD(v, ctrl) \
    ((v) + __int_as_float(__builtin_amdgcn_update_dpp(0, __float_as_int(v), (ctrl), 0xF, 0xF, false)))

__device__ __forceinline__ float wave_sum_dpp(float v) {
    v = DPP_ADD(v, 0xB1);   // quad xor1
    v = DPP_ADD(v, 0x4E);   // quad xor2
    v = DPP_ADD(v, 0x141);  // half_mirror = xor4
    v = DPP_ADD(v, 0x140);  // row_mirror = xor8
    v = DPP_ADD(v, 0x142);  // row_bcast15
    v = DPP_ADD(v, 0x143);  // row_bcast31
    return v;               // lane 63 holds full 64-lane sum
}

__global__ __launch_bounds__(NTH, 1) void rnn_fused(
    const float* __restrict__ x,     // [T][B]
    const float* __restrict__ h0,    // [B][H]
    const float* __restrict__ Wih,   // [H]
    const float* __restrict__ Whh,   // [H][H]
    const float* __restrict__ bih,   // [H]
    const float* __restrict__ bhh,   // [H]
    const float* __restrict__ Wlin,  // [H]
    const float* __restrict__ blin,  // [1]
    float* __restrict__ y,           // [T][B]
    float* __restrict__ hN)          // [B][H]
{
    __shared__ float xsh[TT];        // this block's x column
    __shared__ float ysum[NW][TT];   // per-wave y partials
    __shared__ float hsh[2][HH];     // ping-pong h state

    const int b    = blockIdx.x;
    const int tid  = threadIdx.x;
    const int w    = tid >> 6;       // wave 0..3
    const int lane = tid & 63;
    const int hl   = lane >> 2;      // 0..15
    const int ks   = lane & 3;       // K-split 0..3
    const int h    = w * 16 + hl;    // output index 0..63

    // ---- Prologue ----
    const float* xb = x + b;
    for (int i = tid; i < TT; i += NTH)
        xsh[i] = xb[(size_t)i * BB];

    // W_hh[h][ks*16 .. ks*16+15] in registers
    float wr[16];
    const float* wp = Whh + h * HH + ks * 16;
#pragma unroll
    for (int i = 0; i < 4; ++i) {
        const float4 v4 = *reinterpret_cast<const float4*>(wp + 4 * i);
        wr[4 * i + 0] = v4.x; wr[4 * i + 1] = v4.y;
        wr[4 * i + 2] = v4.z; wr[4 * i + 3] = v4.w;
    }
    const float wih  = Wih[h];
    const float bias = bih[h] + bhh[h];
    const float wlin = Wlin[h];
    const float bl   = blin[0];

    if (tid < HH) hsh[0][tid] = h0[b * HH + tid];
    __syncthreads();

    float hval = 0.f;

    // ---- Recurrence: one barrier per step, ping-pong hsh ----
#pragma unroll 1
    for (int t = 0; t < TT; t += 2) {
#pragma unroll
        for (int u = 0; u < 2; ++u) {
            const int tt = t + u;

            // read my K-slice of h_prev from hsh[u] (4 distinct addrs/wave, ~2-way max)
            float hb[16];
#pragma unroll
            for (int i = 0; i < 4; ++i) {
                const float4 v4 = *reinterpret_cast<const float4*>(&hsh[u][ks * 16 + 4 * i]);
                hb[4 * i + 0] = v4.x; hb[4 * i + 1] = v4.y;
                hb[4 * i + 2] = v4.z; hb[4 * i + 3] = v4.w;
            }
            const float xt = xsh[tt];

            // partial dot over K=16, 2 chains
            float a0 = 0.f, a1 = 0.f;
#pragma unroll
            for (int i = 0; i < 16; i += 2) {
                a0 = fmaf(hb[i + 0], wr[i + 0], a0);
                a1 = fmaf(hb[i + 1], wr[i + 1], a1);
            }
            float s = a0 + a1;
            // quad reduce: all 4 lanes of the quad end with the full K=64 dot
            s = DPP_ADD(s, 0xB1);
            s = DPP_ADD(s, 0x4E);

            const float acc = fmaf(xt, wih, bias) + s;

            // tanh via exp; saturates correctly
            const float e2 = __expf(acc + acc);
            hval = 1.0f - __fdividef(2.0f, e2 + 1.0f);

            // publish h_{t+1} into the other buffer, then the step barrier
            if (ks == 0) hsh[u ^ 1][h] = hval;
            __syncthreads();

            // y partial — AFTER the barrier, off the recurrence critical path
            float yv = (ks == 0) ? hval * wlin : 0.f;
            float sy = wave_sum_dpp(yv);
            if (lane == 63) ysum[w][tt] = sy;
        }
    }

    // ---- Epilogue ----
    __syncthreads();
    for (int i = tid; i < TT; i += NTH)
        y[(size_t)i * BB + b] = ysum[0][i] + ysum[1][i] + ysum[2][i] + ysum[3][i] + bl;
    if (ks == 0) hN[b * HH + h] = hval;
}

extern "C" void kernel_launch(void* const* d_in, const int* in_sizes, int n_in,
                              void* d_out, int out_size, void* d_ws, size_t ws_size,
                              hipStream_t stream) {
    const float* x    = (const float*)d_in[0];
    const float* h0   = (const float*)d_in[1];
    const float* Wih  = (const float*)d_in[2];
    const float* Whh  = (const float*)d_in[3];
    const float* bih  = (const float*)d_in[4];
    const float* bhh  = (const float*)d_in[5];
    const float* Wlin = (const float*)d_in[6];
    const float* blin = (const float*)d_in[7];

    float* y  = (float*)d_out;            // [T*B]
    float* hN = (float*)d_out + TT * BB;  // [B*H]

    rnn_fused<<<dim3(BB), dim3(NTH), 0, stream>>>(x, h0, Wih, Whh, bih, bhh, Wlin, blin, y, hN);
}

// Round 9
// 510.688 us; speedup vs baseline: 2.2084x; 1.0359x over previous
//
#include <hip/hip_runtime.h>

#define TT 2048
#define BB 512
#define HH 64
#define NW 4
#define NTH (NW * 64)   // 256 threads
#define HIST 128        // history ring length
#define HPAD 68         // floats per hist row (272 B: 16B-aligned, bank-skewed)

typedef float f32x2 __attribute__((ext_vector_type(2)));
typedef float f32x4 __attribute__((ext_vector_type(4)));

// quad DPP adds (ctrl is a literal)
#define DPP_ADD(v, ctrl) \
    ((v) + __int_as_float(__builtin_amdgcn_update_dpp(0, __float_as_int(v), (ctrl), 0xF, 0xF, false)))

__global__ __launch_bounds__(NTH, 1) void rnn_fused(
    const float* __restrict__ x,     // [T][B]
    const float* __restrict__ h0,    // [B][H]
    const float* __restrict__ Wih,   // [H]
    const float* __restrict__ Whh,   // [H][H]
    const float* __restrict__ bih,   // [H]
    const float* __restrict__ bhh,   // [H]
    const float* __restrict__ Wlin,  // [H]
    const float* __restrict__ blin,  // [1]
    float* __restrict__ y,           // [T][B]
    float* __restrict__ hN)          // [B][H]
{
    __shared__ __align__(16) float hist[HIST][HPAD];  // fp32 h ring
    __shared__ float xsh[TT];                         // this block's x column
    __shared__ __align__(16) float wlin_sh[HH];

    const int b    = blockIdx.x;
    const int tid  = threadIdx.x;
    const int lane = tid & 63;
    const int w    = tid >> 6;       // wave 0..3
    const int hl   = lane >> 2;      // 0..15
    const int ks   = lane & 3;       // K-split 0..3
    const int h    = w * 16 + hl;    // output index 0..63

    // ---- Prologue ----
    for (int i = tid; i < TT; i += NTH)
        xsh[i] = x[(size_t)i * BB + b];

    // W_hh[h][ks*16 .. ks*16+15] as 8 packed f32x2 in registers
    f32x2 wr[8];
    const float* wp = Whh + h * HH + ks * 16;
#pragma unroll
    for (int i = 0; i < 8; ++i) {
        wr[i][0] = wp[2 * i + 0];
        wr[i][1] = wp[2 * i + 1];
    }
    const float wih  = Wih[h];
    const float bias = bih[h] + bhh[h];
    const float bl   = blin[0];

    if (tid < HH) {
        hist[HIST - 1][tid] = h0[b * HH + tid];  // slot 127 = h_0
        wlin_sh[tid] = Wlin[tid];
    }
    __syncthreads();

    float hval = 0.f;

    // ---- Recurrence: one barrier per step; bulk y every HIST steps ----
#pragma unroll 1
    for (int tc = 0; tc < TT; tc += HIST) {
#pragma unroll 2
        for (int ti = 0; ti < HIST; ++ti) {
            const int t  = tc + ti;
            const int rs = (ti + HIST - 1) & (HIST - 1);  // slot of h_{t-1}

            const float xt = xsh[t];

            // my K=16 slice of h_prev: 4 x ds_read_b128 (4 distinct addrs/wave)
            const f32x4* hp = reinterpret_cast<const f32x4*>(&hist[rs][ks * 16]);
            const f32x4 q0 = hp[0], q1 = hp[1], q2 = hp[2], q3 = hp[3];

            // 8 v_pk_fma_f32 in 4 independent chains
            f32x2 a01 = {0.f, 0.f}, a23 = {0.f, 0.f};
            f32x2 a45 = {0.f, 0.f}, a67 = {0.f, 0.f};
            a01 = __builtin_elementwise_fma(__builtin_shufflevector(q0, q0, 0, 1), wr[0], a01);
            a23 = __builtin_elementwise_fma(__builtin_shufflevector(q0, q0, 2, 3), wr[1], a23);
            a45 = __builtin_elementwise_fma(__builtin_shufflevector(q1, q1, 0, 1), wr[2], a45);
            a67 = __builtin_elementwise_fma(__builtin_shufflevector(q1, q1, 2, 3), wr[3], a67);
            a01 = __builtin_elementwise_fma(__builtin_shufflevector(q2, q2, 0, 1), wr[4], a01);
            a23 = __builtin_elementwise_fma(__builtin_shufflevector(q2, q2, 2, 3), wr[5], a23);
            a45 = __builtin_elementwise_fma(__builtin_shufflevector(q3, q3, 0, 1), wr[6], a45);
            a67 = __builtin_elementwise_fma(__builtin_shufflevector(q3, q3, 2, 3), wr[7], a67);
            const f32x2 s2 = (a01 + a23) + (a45 + a67);
            float s = s2[0] + s2[1];

            // complete K=64 across the 4-lane quad
            s = DPP_ADD(s, 0xB1);  // xor1
            s = DPP_ADD(s, 0x4E);  // xor2

            const float acc = fmaf(xt, wih, bias) + s;

            // tanh(acc) = 1 - 2/(e^{2acc}+1); saturates correctly for large |acc|
            const float e2 = __expf(acc + acc);
            hval = 1.0f - __fdividef(2.0f, e2 + 1.0f);

            // publish h_t into ring slot ti, then the step barrier
            if (ks == 0) hist[ti][h] = hval;
            __syncthreads();
        }

        // ---- bulk y for this chunk: thread tid (<128) -> t = tc + tid ----
        if (tid < HIST) {
            const f32x4* hp = reinterpret_cast<const f32x4*>(&hist[tid][0]);
            const f32x4* wl = reinterpret_cast<const f32x4*>(&wlin_sh[0]);
            f32x2 acc2 = {0.f, 0.f};
#pragma unroll
            for (int i = 0; i < 16; ++i) {
                const f32x4 q  = hp[i];
                const f32x4 qw = wl[i];
                acc2 = __builtin_elementwise_fma(__builtin_shufflevector(q, q, 0, 1),
                                                 __builtin_shufflevector(qw, qw, 0, 1), acc2);
                acc2 = __builtin_elementwise_fma(__builtin_shufflevector(q, q, 2, 3),
                                                 __builtin_shufflevector(qw, qw, 2, 3), acc2);
            }
            y[(size_t)(tc + tid) * BB + b] = acc2[0] + acc2[1] + bl;
        }
        __syncthreads();  // protect ring from next chunk's writes
    }

    // ---- Epilogue ----
    if (ks == 0) hN[b * HH + h] = hval;
}

extern "C" void kernel_launch(void* const* d_in, const int* in_sizes, int n_in,
                              void* d_out, int out_size, void* d_ws, size_t ws_size,
                              hipStream_t stream) {
    const float* x    = (const float*)d_in[0];
    const float* h0   = (const float*)d_in[1];
    const float* Wih  = (const float*)d_in[2];
    const float* Whh  = (const float*)d_in[3];
    const float* bih  = (const float*)d_in[4];
    const float* bhh  = (const float*)d_in[5];
    const float* Wlin = (const float*)d_in[6];
    const float* blin = (const float*)d_in[7];

    float* y  = (float*)d_out;            // [T*B]
    float* hN = (float*)d_out + TT * BB;  // [B*H]

    rnn_fused<<<dim3(BB), dim3(NTH), 0, stream>>>(x, h0, Wih, Whh, bih, bhh, Wlin, blin, y, hN);
}